// Round 2
// baseline (236.274 us; speedup 1.0000x reference)
//
#include <hip/hip_runtime.h>
#include <math.h>

#define BS 4
#define NC 64
#define CC 256
#define DD 64
#define KK 32
#define ALPHA 8
#define HS 256
#define HM 256
#define HMOD 256
#define MODIN 225   // K + D + 1 + D + D
#define MODOUT 97   // K + 1 + D

// ---------------- Kernel 1: per-(b,n) means over C -> mod_in ----------------
// grid = BS*NC*4; seg 0:h, 1:prim, 2:hebb, 3:dec+mmag (disjoint mi ranges)
__global__ __launch_bounds__(256) void k_means(
    const float* __restrict__ h, const float* __restrict__ dec,
    const float* __restrict__ prim, const float* __restrict__ hebb,
    const float* __restrict__ mmag, float* __restrict__ ws_modin)
{
    const int bn = blockIdx.x >> 2, seg = blockIdx.x & 3;
    const int tid = threadIdx.x;
    __shared__ float4 buf4[256];
    __shared__ float  buf[256];
    const float inv = 1.0f / (float)CC;
    float* mi = ws_modin + (size_t)bn * MODIN;

    if (seg <= 1) {
        // 64-dim means: h -> [32:96), prim -> [97:161)
        const float* src = (seg == 0) ? (h + (size_t)bn * CC * DD)
                                      : (prim + (size_t)bn * CC * DD);
        const int dst = (seg == 0) ? 32 : 97;
        const float4* p4 = (const float4*)src;
        int q = tid & 15, c0 = tid >> 4;
        float4 sum = make_float4(0.f, 0.f, 0.f, 0.f);
        for (int c = c0; c < CC; c += 16) {
            float4 v = p4[c * 16 + q];
            sum.x += v.x; sum.y += v.y; sum.z += v.z; sum.w += v.w;
        }
        buf4[tid] = sum;
        __syncthreads();
        if (tid < 16) {
            float4 t = buf4[tid];
            for (int r = 1; r < 16; r++) {
                float4 v = buf4[r * 16 + tid];
                t.x += v.x; t.y += v.y; t.z += v.z; t.w += v.w;
            }
            mi[dst + tid * 4 + 0] = t.x * inv;
            mi[dst + tid * 4 + 1] = t.y * inv;
            mi[dst + tid * 4 + 2] = t.z * inv;
            mi[dst + tid * 4 + 3] = t.w * inv;
        }
    } else if (seg == 2) {
        // 32-dim mean: hebb -> [0:32)
        const float4* p4 = (const float4*)(hebb + (size_t)bn * CC * KK);
        int q = tid & 7, c0 = tid >> 3;
        float4 sum = make_float4(0.f, 0.f, 0.f, 0.f);
        for (int c = c0; c < CC; c += 32) {
            float4 v = p4[c * 8 + q];
            sum.x += v.x; sum.y += v.y; sum.z += v.z; sum.w += v.w;
        }
        buf4[tid] = sum;
        __syncthreads();
        if (tid < 8) {
            float4 t = buf4[tid];
            for (int r = 1; r < 32; r++) {
                float4 v = buf4[r * 8 + tid];
                t.x += v.x; t.y += v.y; t.z += v.z; t.w += v.w;
            }
            mi[tid * 4 + 0] = t.x * inv;
            mi[tid * 4 + 1] = t.y * inv;
            mi[tid * 4 + 2] = t.z * inv;
            mi[tid * 4 + 3] = t.w * inv;
        }
    } else {
        // scalar means: decay -> [96]; msg_magnitude replicated -> [161:225)
        buf[tid] = dec[(size_t)bn * CC + tid];
        __syncthreads();
        for (int s2 = 128; s2 > 0; s2 >>= 1) {
            if (tid < s2) buf[tid] += buf[tid + s2];
            __syncthreads();
        }
        if (tid == 0) mi[96] = buf[0] * inv;
        __syncthreads();
        buf[tid] = mmag[(size_t)bn * CC + tid];
        __syncthreads();
        for (int s2 = 128; s2 > 0; s2 >>= 1) {
            if (tid < s2) buf[tid] += buf[tid + s2];
            __syncthreads();
        }
        __syncthreads();
        float m = buf[0] * inv;
        if (tid < DD) mi[161 + tid] = m;
    }
}

// ------------- Kernel 2: mod MLP hidden layer (block = (n, h-quarter)) ------
__global__ __launch_bounds__(256) void k_modhid(
    const float* __restrict__ ws_modin, const float* __restrict__ modw1,
    const float* __restrict__ modb1, float* __restrict__ ws_hid)
{
    const int n = blockIdx.x >> 2, hq = blockIdx.x & 3;
    const int tid = threadIdx.x;
    __shared__ float mi[BS][MODIN];
    for (int i = tid; i < BS * MODIN; i += 256) {
        int b = i / MODIN, j = i - b * MODIN;
        mi[b][j] = ws_modin[(size_t)(b * NC + n) * MODIN + j];
    }
    __syncthreads();
    const int hl = tid >> 2, b = tid & 3;
    const int hh = hq * 64 + hl;
    const float* w = modw1 + ((size_t)n * HMOD + hh) * MODIN;
    float acc = modb1[n * HMOD + hh];
    for (int i = 0; i < MODIN; i++) acc += mi[b][i] * w[i];
    ws_hid[(size_t)(b * NC + n) * HMOD + hh] = tanhf(acc);
}

// ------------- Kernel 3: mod MLP output layer (block = n) -------------------
// thread = (b = tid&3, o0 = tid>>2 [, o1 = o0+64]); hid tile in registers
__global__ __launch_bounds__(256) void k_modout(
    const float* __restrict__ ws_hid, const float* __restrict__ modw2,
    const float* __restrict__ modb2, float* __restrict__ ws_par)
{
    const int n = blockIdx.x, tid = threadIdx.x;
    __shared__ alignas(16) float hid[BS][HMOD];
    for (int i = tid; i < BS * HMOD; i += 256) {
        int b = i >> 8, j = i & 255;
        hid[b][j] = ws_hid[(size_t)(b * NC + n) * HMOD + j];
    }
    __syncthreads();
    const int b = tid & 3, o0 = tid >> 2;   // o0 in 0..63
    const int o1 = o0 + 64;                 // valid while < 97
    const bool has1 = (o1 < MODOUT);
    const float* wbase = modw2 + (size_t)n * HMOD * MODOUT;
    float acc0 = modb2[n * MODOUT + o0];
    float acc1 = has1 ? modb2[n * MODOUT + o1] : 0.f;
    const float4* h4 = (const float4*)hid[b];
    for (int t = 0; t < 64; t++) {          // 4 hh per iteration
        float4 hv = h4[t];
        const float* w = wbase + (size_t)(t * 4) * MODOUT;
        acc0 += hv.x * w[o0] + hv.y * w[MODOUT + o0]
              + hv.z * w[2 * MODOUT + o0] + hv.w * w[3 * MODOUT + o0];
        if (has1)
            acc1 += hv.x * w[o1] + hv.y * w[MODOUT + o1]
                  + hv.z * w[2 * MODOUT + o1] + hv.w * w[3 * MODOUT + o1];
    }
    float* pout = ws_par + (size_t)(b * NC + n) * MODOUT;
    pout[o0] = (o0 < KK) ? (1.0f / (1.0f + expf(-acc0))) : acc0;
    if (has1) pout[o1] = (o1 < KK) ? (1.0f / (1.0f + expf(-acc1))) : acc1;
}

// ------------- Kernel 3b: neuron-id projections (shared across b) -----------
// grid = NC*ALPHA; nts[n][a][hh] = nid . sw1[hh,128:192]; ntm likewise for mw1
__global__ __launch_bounds__(256) void k_nid(
    const float* __restrict__ nid_g, const float* __restrict__ sw1,
    const float* __restrict__ mw1, float* __restrict__ nts,
    float* __restrict__ ntm)
{
    const int n = blockIdx.x >> 3, a = blockIdx.x & 7;
    const int tid = threadIdx.x;  // hh
    __shared__ alignas(16) float nv[DD];
    if (tid < DD) nv[tid] = nid_g[((size_t)n * CC + (CC - ALPHA + a)) * DD + tid];
    __syncthreads();
    const float*  w  = sw1 + (size_t)tid * 193 + 128;        // scalar (odd stride)
    const float4* wm = (const float4*)(mw1 + (size_t)tid * 192 + 128);
    const float4* n4 = (const float4*)nv;
    float acc = 0.f, accm = 0.f;
    for (int d4 = 0; d4 < 16; d4++) {
        float4 v = n4[d4];
        acc  += v.x * w[d4 * 4] + v.y * w[d4 * 4 + 1]
              + v.z * w[d4 * 4 + 2] + v.w * w[d4 * 4 + 3];
        float4 wv = wm[d4];
        accm += v.x * wv.x + v.y * wv.y + v.z * wv.z + v.w * wv.w;
    }
    nts[((size_t)n * ALPHA + a) * HS + tid] = acc;
    ntm[((size_t)n * ALPHA + a) * HM + tid] = accm;
}

// ------------- Kernel 4: per-(b,n) cells, all 8 cells batched ---------------
__global__ __launch_bounds__(256) void k_cells(
    const float* __restrict__ h, const float* __restrict__ pm,
    const int* __restrict__ conn,
    const float* __restrict__ sw1, const float* __restrict__ sb1,
    const float* __restrict__ sw2, const float* __restrict__ sb2,
    const float* __restrict__ mw1, const float* __restrict__ mb1,
    const float* __restrict__ mw2, const float* __restrict__ mb2,
    const float* __restrict__ nid_g, const float* __restrict__ ws_par,
    const float* __restrict__ nts, const float* __restrict__ ntm,
    float* __restrict__ out)
{
    const int b = blockIdx.x >> 6, n = blockIdx.x & 63;
    const int tid = threadIdx.x;

    __shared__ float wsig[KK];
    __shared__ alignas(16) float prm[DD];
    __shared__ int cidx[ALPHA][KK];
    __shared__ alignas(16) float nid_s[ALPHA][DD];
    __shared__ alignas(16) float iv[ALPHA][DD];
    __shared__ alignas(16) float hnew[ALPHA][DD];
    __shared__ alignas(16) float t1[ALPHA][HS];
    __shared__ alignas(16) float hm[ALPHA][HM];
    __shared__ float red[256];
    __shared__ float sdecay_sh, ssig_sh;

    const float* par = ws_par + (size_t)(b * NC + n) * MODOUT;
    if (tid < KK) wsig[tid] = par[tid];
    if (tid == KK) {
        float dr = par[KK];
        sdecay_sh = dr;
        ssig_sh = 1.0f / (1.0f + expf(-dr));
    }
    if (tid > KK && tid < MODOUT) prm[tid - KK - 1] = par[tid];
    {   // conn rows: 8*32 = 256 ints, one per thread
        int a = tid >> 5, k = tid & 31;
        cidx[a][k] = conn[((size_t)n * CC + (CC - ALPHA + a)) * KK + k];
    }
    for (int i = tid; i < ALPHA * DD; i += 256) {
        int a = i >> 6, d = i & 63;
        nid_s[a][d] = nid_g[((size_t)n * CC + (CC - ALPHA + a)) * DD + d];
    }
    __syncthreads();

    // --- base terms (per hh = tid), kept in registers ---
    float base_s, base_m;
    {
        const float* w  = sw1 + (size_t)tid * 193;
        const float* wm = mw1 + (size_t)tid * 192;
        float acc  = sb1[tid] + sdecay_sh * w[192];
        float accm = mb1[tid];
        for (int d = 0; d < DD; d++) {
            float pv = prm[d];
            acc  += pv * w[64 + d];
            accm += pv * wm[64 + d];
        }
        base_s = acc; base_m = accm;
    }

    // --- gather: iv[a][d] = sum_k wsig[k]*pm[.., cidx[a][k], d] ---
    const size_t pmbase = (size_t)(b * NC + n) * CC * DD;
    {
        const int d = tid & 63, ag = tid >> 6;
        for (int half = 0; half < 2; half++) {
            int a = ag + half * 4;
            float acc = 0.f;
            for (int k = 0; k < KK; k++)
                acc += wsig[k] * pm[pmbase + (size_t)cidx[a][k] * DD + d];
            iv[a][d] = acc;
        }
    }
    __syncthreads();

    // --- state hidden: t1[a][hh], hh = tid, 8 accumulators ---
    {
        const float* w = sw1 + (size_t)tid * 193;
        float acc[ALPHA];
        if (nts) {
            const float* p = nts + (size_t)n * ALPHA * HS + tid;
            for (int a = 0; a < ALPHA; a++) acc[a] = base_s + p[(size_t)a * HS];
        } else {
            for (int a = 0; a < ALPHA; a++) acc[a] = base_s;
        }
        for (int d4 = 0; d4 < 16; d4++) {
            float w0 = w[d4 * 4], w1 = w[d4 * 4 + 1],
                  w2 = w[d4 * 4 + 2], w3 = w[d4 * 4 + 3];
            for (int a = 0; a < ALPHA; a++) {
                float4 v = ((const float4*)iv[a])[d4];
                acc[a] += v.x * w0 + v.y * w1 + v.z * w2 + v.w * w3;
            }
            if (!nts) {
                float u0 = w[128 + d4 * 4], u1 = w[128 + d4 * 4 + 1],
                      u2 = w[128 + d4 * 4 + 2], u3 = w[128 + d4 * 4 + 3];
                for (int a = 0; a < ALPHA; a++) {
                    float4 v = ((const float4*)nid_s[a])[d4];
                    acc[a] += v.x * u0 + v.y * u1 + v.z * u2 + v.w * u3;
                }
            }
        }
        for (int a = 0; a < ALPHA; a++) t1[a][tid] = tanhf(acc[a]);
    }
    __syncthreads();

    // --- update + h_new: thread = (d, ag), 2 cells each, full 256-hh dot ---
    {
        const int d = tid & 63, ag = tid >> 6;
        const float4* w4  = (const float4*)(sw2 + (size_t)d * HS);
        const float4* t40 = (const float4*)t1[ag];
        const float4* t41 = (const float4*)t1[ag + 4];
        float acc0 = 0.f, acc1 = 0.f;
        for (int t = 0; t < 64; t++) {
            float4 wv = w4[t];
            float4 a0 = t40[t], a1 = t41[t];
            acc0 += wv.x * a0.x + wv.y * a0.y + wv.z * a0.z + wv.w * a0.w;
            acc1 += wv.x * a1.x + wv.y * a1.y + wv.z * a1.z + wv.w * a1.w;
        }
        float bb = sb2[d], sg = ssig_sh;
        float u0 = tanhf(acc0 + bb), u1 = tanhf(acc1 + bb);
        float h0 = h[pmbase + (size_t)(CC - ALPHA + ag) * DD + d];
        float h1 = h[pmbase + (size_t)(CC - ALPHA + ag + 4) * DD + d];
        hnew[ag][d]     = sg * h0 + (1.f - sg) * u0;
        hnew[ag + 4][d] = sg * h1 + (1.f - sg) * u1;
    }
    __syncthreads();

    // --- msg hidden: hm[a][hh], hh = tid ---
    {
        const float4* w4 = (const float4*)(mw1 + (size_t)tid * 192);
        float acc[ALPHA];
        if (ntm) {
            const float* p = ntm + (size_t)n * ALPHA * HM + tid;
            for (int a = 0; a < ALPHA; a++) acc[a] = base_m + p[(size_t)a * HM];
        } else {
            for (int a = 0; a < ALPHA; a++) acc[a] = base_m;
        }
        for (int d4 = 0; d4 < 16; d4++) {
            float4 wv = w4[d4];
            for (int a = 0; a < ALPHA; a++) {
                float4 v = ((const float4*)hnew[a])[d4];
                acc[a] += wv.x * v.x + wv.y * v.y + wv.z * v.z + wv.w * v.w;
            }
            if (!ntm) {
                float4 uv = w4[32 + d4];   // +128 floats
                for (int a = 0; a < ALPHA; a++) {
                    float4 v = ((const float4*)nid_s[a])[d4];
                    acc[a] += uv.x * v.x + uv.y * v.y + uv.z * v.z + uv.w * v.w;
                }
            }
        }
        for (int a = 0; a < ALPHA; a++) hm[a][tid] = tanhf(acc[a]);
    }
    __syncthreads();

    // --- msg out + readout mean over the 8 cells ---
    {
        const int d = tid & 63, ag = tid >> 6;
        const float4* w4  = (const float4*)(mw2 + (size_t)d * HM);
        const float4* m40 = (const float4*)hm[ag];
        const float4* m41 = (const float4*)hm[ag + 4];
        float acc0 = 0.f, acc1 = 0.f;
        for (int t = 0; t < 64; t++) {
            float4 wv = w4[t];
            float4 a0 = m40[t], a1 = m41[t];
            acc0 += wv.x * a0.x + wv.y * a0.y + wv.z * a0.z + wv.w * a0.w;
            acc1 += wv.x * a1.x + wv.y * a1.y + wv.z * a1.z + wv.w * a1.w;
        }
        float bb = mb2[d];
        red[tid] = tanhf(acc0 + bb) + tanhf(acc1 + bb);
    }
    __syncthreads();
    if (tid < DD)
        out[(size_t)(b * NC + n) * DD + tid] =
            (red[tid] + red[tid + 64] + red[tid + 128] + red[tid + 192]) * 0.125f;
}

extern "C" void kernel_launch(void* const* d_in, const int* in_sizes, int n_in,
                              void* d_out, int out_size, void* d_ws, size_t ws_size,
                              hipStream_t stream) {
    const float* h     = (const float*)d_in[0];
    const float* pm    = (const float*)d_in[1];
    const float* dec   = (const float*)d_in[2];
    const float* prim  = (const float*)d_in[3];
    const float* hebb  = (const float*)d_in[4];
    const float* mmag  = (const float*)d_in[5];
    // d_in[6] cc_signals: provably unused (injection hits cells 0..7 only;
    // readout reads cells 248..255)
    const float* sw1   = (const float*)d_in[7];
    const float* sb1   = (const float*)d_in[8];
    const float* sw2   = (const float*)d_in[9];
    const float* sb2   = (const float*)d_in[10];
    const float* mw1   = (const float*)d_in[11];
    const float* mb1   = (const float*)d_in[12];
    const float* mw2   = (const float*)d_in[13];
    const float* mb2   = (const float*)d_in[14];
    const float* modw1 = (const float*)d_in[15];
    const float* modb1 = (const float*)d_in[16];
    const float* modw2 = (const float*)d_in[17];
    const float* modb2 = (const float*)d_in[18];
    const float* nid   = (const float*)d_in[19];
    const int*   conn  = (const int*)d_in[20];
    float* out = (float*)d_out;

    float* ws       = (float*)d_ws;
    float* ws_modin = ws;                       // 256*225 = 57600
    float* ws_hid   = ws + 57600;               // 256*256 = 65536
    float* ws_par   = ws + 57600 + 65536;       // 256*97  = 24832
    float* nts      = ws + 147968;              // 64*8*256 = 131072
    float* ntm      = ws + 147968 + 131072;     // 131072
    const bool use_nt = ws_size >= (size_t)(147968 + 2 * 131072) * sizeof(float);

    if (use_nt)
        k_nid<<<NC * ALPHA, 256, 0, stream>>>(nid, sw1, mw1, nts, ntm);
    k_means <<<BS * NC * 4, 256, 0, stream>>>(h, dec, prim, hebb, mmag, ws_modin);
    k_modhid<<<NC * 4, 256, 0, stream>>>(ws_modin, modw1, modb1, ws_hid);
    k_modout<<<NC, 256, 0, stream>>>(ws_hid, modw2, modb2, ws_par);
    k_cells <<<BS * NC, 256, 0, stream>>>(h, pm, conn, sw1, sb1, sw2, sb2,
                                          mw1, mb1, mw2, mb2, nid, ws_par,
                                          use_nt ? nts : nullptr,
                                          use_nt ? ntm : nullptr, out);
}